// Round 1
// baseline (470.392 us; speedup 1.0000x reference)
//
#include <hip/hip_runtime.h>

#define N_NODES_C 50000
#define N_EDGES_C 600000
#define DIM 128

// ---------------- CSR build ----------------

__global__ void count_kernel(const int* __restrict__ dst, int* __restrict__ deg, int nE) {
    int e = blockIdx.x * blockDim.x + threadIdx.x;
    if (e < nE) atomicAdd(&deg[dst[e]], 1);
}

// single-block exclusive scan: offsets[0]=0, offsets[i+1]=sum(deg[0..i])
__global__ void scan_kernel(const int* __restrict__ deg, int* __restrict__ offsets, int n) {
    __shared__ int buf[1024];
    __shared__ int carry;
    const int tid = threadIdx.x;
    if (tid == 0) { carry = 0; offsets[0] = 0; }
    __syncthreads();
    for (int base = 0; base < n; base += 1024) {
        int i = base + tid;
        int v = (i < n) ? deg[i] : 0;
        buf[tid] = v;
        __syncthreads();
        for (int off = 1; off < 1024; off <<= 1) {
            int t = (tid >= off) ? buf[tid - off] : 0;
            __syncthreads();
            buf[tid] += t;
            __syncthreads();
        }
        int incl = buf[tid] + carry;
        if (i < n) offsets[i + 1] = incl;
        __syncthreads();
        if (tid == 1023) carry = incl;
        __syncthreads();
    }
}

__global__ void fill_kernel(const int* __restrict__ src, const int* __restrict__ dst,
                            const int* __restrict__ offsets, int* __restrict__ cursor,
                            int* __restrict__ esrc, int nE) {
    int e = blockIdx.x * blockDim.x + threadIdx.x;
    if (e < nE) {
        int d = dst[e];
        int pos = atomicAdd(&cursor[d], 1);
        esrc[offsets[d] + pos] = src[e];
    }
}

// ---------------- fused node kernel ----------------
// 256 threads = (j in 0..127) x (kh in 0..1). W row slice held in registers.
// Phase A: gather-mean over incoming edges (kh-halves split edges).
// Phase B: out[j] = sum_k concat[k] * W[j][k]; L2-normalize; relu; *snorm.

__launch_bounds__(256, 2)
__global__ void node_kernel(const float* __restrict__ h, const float* __restrict__ snorm,
                            const float* __restrict__ W, const int* __restrict__ offsets,
                            const int* __restrict__ esrc, float* __restrict__ out, int nNodes) {
    __shared__ __align__(16) float concat[2 * DIM];
    __shared__ float partial[256];
    __shared__ float red[4];

    const int tid = threadIdx.x;
    const int j   = tid & (DIM - 1);   // output dim / feature dim
    const int kh  = tid >> 7;          // which K-half of the 256-wide dot

    // W[j][kh*128 .. kh*128+127] in registers (32 float4 = 128 VGPR)
    float4 w4[32];
    const float4* Wp = reinterpret_cast<const float4*>(W + j * (2 * DIM) + kh * DIM);
#pragma unroll
    for (int i = 0; i < 32; ++i) w4[i] = Wp[i];

    for (int n = blockIdx.x; n < nNodes; n += gridDim.x) {
        const int start = offsets[n];
        const int end   = offsets[n + 1];
        const int deg   = end - start;

        // ---- Phase A: gather mean (each kh-half takes alternate edges) ----
        float a0 = 0.f, a1 = 0.f, a2 = 0.f, a3 = 0.f;
        int e = start + kh;
        for (; e + 6 < end; e += 8) {
            int s0 = esrc[e];
            int s1 = esrc[e + 2];
            int s2 = esrc[e + 4];
            int s3 = esrc[e + 6];
            a0 += h[s0 * DIM + j];
            a1 += h[s1 * DIM + j];
            a2 += h[s2 * DIM + j];
            a3 += h[s3 * DIM + j];
        }
        for (; e < end; e += 2) a0 += h[esrc[e] * DIM + j];
        partial[tid] = (a0 + a1) + (a2 + a3);
        if (kh == 0) concat[j] = h[n * DIM + j];   // self features
        __syncthreads();
        if (kh == 1) {
            float inv = 1.0f / (float)((deg > 1) ? deg : 1);
            concat[DIM + j] = (partial[j] + partial[DIM + j]) * inv;
        }
        __syncthreads();

        // ---- Phase B: half-dot per thread ----
        float s = 0.f;
        const float4* c4p = reinterpret_cast<const float4*>(&concat[kh * DIM]);
#pragma unroll
        for (int i = 0; i < 32; ++i) {
            float4 c4 = c4p[i];   // wave-uniform LDS broadcast
            s = fmaf(c4.x, w4[i].x, s);
            s = fmaf(c4.y, w4[i].y, s);
            s = fmaf(c4.z, w4[i].z, s);
            s = fmaf(c4.w, w4[i].w, s);
        }
        __syncthreads();          // partial (phase A values) fully consumed
        partial[tid] = s;
        __syncthreads();
        float bj = partial[j] + partial[DIM + j];

        // ---- L2 norm over 128 outputs ----
        float sq = bj * bj;
#pragma unroll
        for (int off = 32; off > 0; off >>= 1) sq += __shfl_xor(sq, off);
        if ((tid & 63) == 0) red[tid >> 6] = sq;
        __syncthreads();
        float nrm   = sqrtf(red[0] + red[1]);
        float scale = 1.0f / fmaxf(nrm, 1e-12f);
        if (tid < DIM) {
            float o = fmaxf(bj * scale, 0.0f) * snorm[n];
            out[n * DIM + tid] = o;
        }
        __syncthreads();          // before LDS reuse next iteration
    }
}

// ---------------- launcher ----------------

extern "C" void kernel_launch(void* const* d_in, const int* in_sizes, int n_in,
                              void* d_out, int out_size, void* d_ws, size_t ws_size,
                              hipStream_t stream) {
    const float* h     = (const float*)d_in[0];
    const float* snorm = (const float*)d_in[1];
    const float* W     = (const float*)d_in[2];
    const int*   src   = (const int*)d_in[3];
    const int*   dst   = (const int*)d_in[4];
    float*       out   = (float*)d_out;

    char* ws = (char*)d_ws;
    int* deg     = (int*)(ws + 0);          // 50000 ints
    int* cursor  = (int*)(ws + 200000);     // 50000 ints
    int* offsets = (int*)(ws + 400000);     // 50001 ints
    int* esrc    = (int*)(ws + 600064);     // 600000 ints

    // zero deg + cursor (contiguous)
    hipMemsetAsync(ws, 0, 400000, stream);

    const int eblocks = (N_EDGES_C + 255) / 256;
    count_kernel<<<eblocks, 256, 0, stream>>>(dst, deg, N_EDGES_C);
    scan_kernel<<<1, 1024, 0, stream>>>(deg, offsets, N_NODES_C);
    fill_kernel<<<eblocks, 256, 0, stream>>>(src, dst, offsets, cursor, esrc, N_EDGES_C);
    node_kernel<<<1024, 256, 0, stream>>>(h, snorm, W, offsets, esrc, out, N_NODES_C);
}

// Round 2
// 306.509 us; speedup vs baseline: 1.5347x; 1.5347x over previous
//
#include <hip/hip_runtime.h>

#define N_NODES_C 50000
#define N_EDGES_C 600000
#define DIM 128

// ---------------- CSR build ----------------

__global__ void count_kernel(const int* __restrict__ dst, int* __restrict__ deg, int nE) {
    int e = blockIdx.x * blockDim.x + threadIdx.x;
    if (e < nE) atomicAdd(&deg[dst[e]], 1);
}

// two-level scan: scan1 (per-block inclusive) -> scan2 (block sums) -> scan3 (add bases)
__global__ void scan1_kernel(const int* __restrict__ deg, int* __restrict__ offs,
                             int* __restrict__ bsum, int n) {
    __shared__ int buf[256];
    const int t = threadIdx.x;
    const int i = blockIdx.x * 256 + t;
    int v = (i < n) ? deg[i] : 0;
    buf[t] = v;
    __syncthreads();
    for (int off = 1; off < 256; off <<= 1) {
        int x = (t >= off) ? buf[t - off] : 0;
        __syncthreads();
        buf[t] += x;
        __syncthreads();
    }
    if (i < n) offs[i + 1] = buf[t];
    if (t == 255) bsum[blockIdx.x] = buf[255];
}

__global__ void scan2_kernel(int* __restrict__ bsum, int nb) {
    __shared__ int buf[256];
    const int t = threadIdx.x;
    int v = (t < nb) ? bsum[t] : 0;
    buf[t] = v;
    __syncthreads();
    for (int off = 1; off < 256; off <<= 1) {
        int x = (t >= off) ? buf[t - off] : 0;
        __syncthreads();
        buf[t] += x;
        __syncthreads();
    }
    if (t < nb) bsum[t] = (t == 0) ? 0 : buf[t - 1];   // exclusive base per block
}

__global__ void scan3_kernel(int* __restrict__ offs, const int* __restrict__ bsum, int n) {
    const int i = blockIdx.x * 256 + threadIdx.x;
    if (i < n) offs[i + 1] += bsum[i >> 8];
    if (i == 0) offs[0] = 0;
}

__global__ void fill_kernel(const int* __restrict__ src, const int* __restrict__ dst,
                            const int* __restrict__ offsets, int* __restrict__ cursor,
                            int* __restrict__ esrc, int nE) {
    int e = blockIdx.x * blockDim.x + threadIdx.x;
    if (e < nE) {
        int d = dst[e];
        int pos = atomicAdd(&cursor[d], 1);
        esrc[offsets[d] + pos] = src[e];
    }
}

// ---------------- fused node kernel ----------------
// 512 threads. Phase A: thread=(col4 0..31, eq 0..15); each wave gathers whole
// 512B rows coalesced; 16-way edge split. Phase B: thread=(j 0..127, kq 0..3);
// W[j][kq*64..+63] pinned in 64 VGPRs; 4 independent FMA accumulators.

__launch_bounds__(512, 4)
__global__ void node_kernel(const float* __restrict__ h, const float* __restrict__ snorm,
                            const float* __restrict__ W, const int* __restrict__ offsets,
                            const int* __restrict__ esrc, float* __restrict__ out, int nNodes) {
    __shared__ __align__(16) float p4[512 * 4];   // phase-A float4 partials / phase-B scalar partials
    __shared__ __align__(16) float concat[2 * DIM];
    __shared__ float red[8];

    const int tid  = threadIdx.x;
    const int j    = tid & 127;   // output dim (phase B)
    const int kq   = tid >> 7;    // K-quarter 0..3 (phase B)
    const int col4 = tid & 31;    // float4 column (phase A)
    const int eq   = tid >> 5;    // edge slot 0..15 (phase A)

    // W[j][kq*64 .. +63] pinned in registers (16 float4 = 64 VGPR)
    float4 w[16];
    const float4* Wp = reinterpret_cast<const float4*>(W + j * (2 * DIM) + kq * 64);
#pragma unroll
    for (int i = 0; i < 16; ++i) w[i] = Wp[i];
#pragma unroll
    for (int i = 0; i < 16; ++i)
        asm volatile("" : "+v"(w[i].x), "+v"(w[i].y), "+v"(w[i].z), "+v"(w[i].w));

    for (int n = blockIdx.x; n < nNodes; n += gridDim.x) {
        const int start = offsets[n];
        const int end   = offsets[n + 1];

        // ---- Phase A: coalesced row gather, 16-way edge split ----
        float4 a = {0.f, 0.f, 0.f, 0.f};
        for (int e = start + eq; e < end; e += 16) {
            const int s = esrc[e];
            const float4 v = *reinterpret_cast<const float4*>(h + s * DIM + col4 * 4);
            a.x += v.x; a.y += v.y; a.z += v.z; a.w += v.w;
        }
        *reinterpret_cast<float4*>(&p4[tid * 4]) = a;
        __syncthreads();

        if (tid < 32) {
            float4 c = {0.f, 0.f, 0.f, 0.f};
#pragma unroll
            for (int q = 0; q < 16; ++q) {
                const float4 v = *reinterpret_cast<const float4*>(&p4[(q * 32 + tid) * 4]);
                c.x += v.x; c.y += v.y; c.z += v.z; c.w += v.w;
            }
            const int  deg = end - start;
            const float inv = 1.0f / (float)(deg > 1 ? deg : 1);
            c.x *= inv; c.y *= inv; c.z *= inv; c.w *= inv;
            *reinterpret_cast<float4*>(&concat[DIM + tid * 4]) = c;
            *reinterpret_cast<float4*>(&concat[tid * 4]) =
                *reinterpret_cast<const float4*>(h + n * DIM + tid * 4);
        }
        __syncthreads();

        // ---- Phase B: quarter-dot, 4 independent accumulators ----
        float s0 = 0.f, s1 = 0.f, s2 = 0.f, s3 = 0.f;
        const float4* c4 = reinterpret_cast<const float4*>(&concat[kq * 64]);
#pragma unroll
        for (int i = 0; i < 16; ++i) {
            const float4 c = c4[i];   // wave-uniform LDS broadcast
            s0 = fmaf(c.x, w[i].x, s0);
            s1 = fmaf(c.y, w[i].y, s1);
            s2 = fmaf(c.z, w[i].z, s2);
            s3 = fmaf(c.w, w[i].w, s3);
        }
        p4[tid] = (s0 + s1) + (s2 + s3);   // reuse p4 as scalar partials
        __syncthreads();

        float bj = 0.f;
        if (tid < 128) bj = (p4[j] + p4[DIM + j]) + (p4[2 * DIM + j] + p4[3 * DIM + j]);

        // ---- L2 norm over the 128 outputs ----
        float sq = bj * bj;
#pragma unroll
        for (int off = 32; off > 0; off >>= 1) sq += __shfl_xor(sq, off);
        if (tid < 128 && (tid & 63) == 0) red[tid >> 6] = sq;
        __syncthreads();

        if (tid < 128) {
            const float nrm   = sqrtf(red[0] + red[1]);
            const float scale = 1.0f / fmaxf(nrm, 1e-12f);
            out[n * DIM + tid] = fmaxf(bj * scale, 0.0f) * snorm[n];
        }
        // no trailing barrier needed: all LDS reads of this iter happen before
        // the barriers above; next-iter writes are fenced by those barriers.
    }
}

// ---------------- launcher ----------------

extern "C" void kernel_launch(void* const* d_in, const int* in_sizes, int n_in,
                              void* d_out, int out_size, void* d_ws, size_t ws_size,
                              hipStream_t stream) {
    const float* h     = (const float*)d_in[0];
    const float* snorm = (const float*)d_in[1];
    const float* W     = (const float*)d_in[2];
    const int*   src   = (const int*)d_in[3];
    const int*   dst   = (const int*)d_in[4];
    float*       out   = (float*)d_out;

    char* ws = (char*)d_ws;
    int* deg     = (int*)(ws + 0);          // 50000 ints
    int* cursor  = (int*)(ws + 200000);     // 50000 ints
    int* offsets = (int*)(ws + 400000);     // 50001 ints
    int* bsum    = (int*)(ws + 600416);     // 196 ints
    int* esrc    = (int*)(ws + 601216);     // 600000 ints

    // zero deg + cursor (contiguous)
    hipMemsetAsync(ws, 0, 400000, stream);

    const int eblocks = (N_EDGES_C + 255) / 256;
    const int nblocks = (N_NODES_C + 255) / 256;   // 196
    count_kernel<<<eblocks, 256, 0, stream>>>(dst, deg, N_EDGES_C);
    scan1_kernel<<<nblocks, 256, 0, stream>>>(deg, offsets, bsum, N_NODES_C);
    scan2_kernel<<<1, 256, 0, stream>>>(bsum, nblocks);
    scan3_kernel<<<nblocks, 256, 0, stream>>>(offsets, bsum, N_NODES_C);
    fill_kernel<<<eblocks, 256, 0, stream>>>(src, dst, offsets, cursor, esrc, N_EDGES_C);
    node_kernel<<<1024, 512, 0, stream>>>(h, snorm, W, offsets, esrc, out, N_NODES_C);
}

// Round 3
// 248.063 us; speedup vs baseline: 1.8963x; 1.2356x over previous
//
#include <hip/hip_runtime.h>

#define N_NODES_C 50000
#define N_EDGES_C 600000
#define DIM 128

// ---------------- CSR build ----------------

__global__ void count_kernel(const int* __restrict__ dst, int* __restrict__ deg, int nE) {
    int e = blockIdx.x * blockDim.x + threadIdx.x;
    if (e < nE) atomicAdd(&deg[dst[e]], 1);
}

__global__ void scan1_kernel(const int* __restrict__ deg, int* __restrict__ offs,
                             int* __restrict__ bsum, int n) {
    __shared__ int buf[256];
    const int t = threadIdx.x;
    const int i = blockIdx.x * 256 + t;
    int v = (i < n) ? deg[i] : 0;
    buf[t] = v;
    __syncthreads();
    for (int off = 1; off < 256; off <<= 1) {
        int x = (t >= off) ? buf[t - off] : 0;
        __syncthreads();
        buf[t] += x;
        __syncthreads();
    }
    if (i < n) offs[i + 1] = buf[t];
    if (t == 255) bsum[blockIdx.x] = buf[255];
}

__global__ void scan2_kernel(int* __restrict__ bsum, int nb) {
    __shared__ int buf[256];
    const int t = threadIdx.x;
    int v = (t < nb) ? bsum[t] : 0;
    buf[t] = v;
    __syncthreads();
    for (int off = 1; off < 256; off <<= 1) {
        int x = (t >= off) ? buf[t - off] : 0;
        __syncthreads();
        buf[t] += x;
        __syncthreads();
    }
    if (t < nb) bsum[t] = (t == 0) ? 0 : buf[t - 1];
}

__global__ void scan3_kernel(int* __restrict__ offs, const int* __restrict__ bsum, int n) {
    const int i = blockIdx.x * 256 + threadIdx.x;
    if (i < n) offs[i + 1] += bsum[i >> 8];
    if (i == 0) offs[0] = 0;
}

__global__ void fill_kernel(const int* __restrict__ src, const int* __restrict__ dst,
                            const int* __restrict__ offsets, int* __restrict__ cursor,
                            int* __restrict__ esrc, int nE) {
    int e = blockIdx.x * blockDim.x + threadIdx.x;
    if (e < nE) {
        int d = dst[e];
        int pos = atomicAdd(&cursor[d], 1);
        esrc[offsets[d] + pos] = src[e];
    }
}

// ---------------- aggregation: one wave per node, no barriers ----------------
// Lanes preload <=64 edge ids coalesced, shfl-broadcast ids so h-row loads are
// independent. Half-wave (32 lanes = 512B row) per edge; 2 edges in flight.

__global__ void agg_kernel(const float* __restrict__ h, const int* __restrict__ offsets,
                           const int* __restrict__ esrc, float* __restrict__ c, int nNodes) {
    const int tid  = threadIdx.x;
    const int lane = tid & 63;
    const int wid  = tid >> 6;
    const int node = blockIdx.x * 4 + wid;
    if (node >= nNodes) return;

    const int start = offsets[node];
    const int end   = offsets[node + 1];
    const int col4  = lane & 31;
    const int eh    = lane >> 5;          // 0: even edges, 1: odd edges

    float4 acc = {0.f, 0.f, 0.f, 0.f};
    for (int base = start; base < end; base += 64) {
        const int cnt = min(64, end - base);
        const int ev  = (lane < cnt) ? esrc[base + lane] : 0;
        for (int it = 0; 2 * it + eh < cnt; ++it) {
            const int s = __shfl(ev, 2 * it + eh);
            const float4 v = *reinterpret_cast<const float4*>(h + s * DIM + col4 * 4);
            acc.x += v.x; acc.y += v.y; acc.z += v.z; acc.w += v.w;
        }
    }
    // combine the two half-waves
    acc.x += __shfl_xor(acc.x, 32);
    acc.y += __shfl_xor(acc.y, 32);
    acc.z += __shfl_xor(acc.z, 32);
    acc.w += __shfl_xor(acc.w, 32);

    if (lane < 32) {
        const int deg = end - start;
        const float inv = 1.0f / (float)(deg > 1 ? deg : 1);
        float4 o = {acc.x * inv, acc.y * inv, acc.z * inv, acc.w * inv};
        *reinterpret_cast<float4*>(c + node * DIM + col4 * 4) = o;
    }
}

// ---------------- GEMM + L2norm + relu + snorm, 16-node tiles ----------------
// 256 threads = (j 0..127, kh 0..1). W[j][kh*128..+127] pinned in 128 VGPRs.
// 3 barriers per 16 nodes. c is read from (and out written to) d_out in place:
// each block reads only its own 16 rows before overwriting them.

__launch_bounds__(256, 2)
__global__ void gemm_kernel(const float* __restrict__ h, const float* __restrict__ cbuf,
                            const float* __restrict__ snorm, const float* __restrict__ W,
                            float* __restrict__ out, int nNodes) {
    __shared__ __align__(16) float tile[16 * 2 * DIM];   // 16 rows x 256
    __shared__ float par[16 * 2 * DIM];                  // per-node partials
    __shared__ float red[32];

    const int tid = threadIdx.x;
    const int j   = tid & 127;
    const int kh  = tid >> 7;
    const int base = blockIdx.x * 16;

    // W half-row in registers (32 float4 = 128 VGPR), pinned
    float4 w[32];
    const float4* Wp = reinterpret_cast<const float4*>(W + j * (2 * DIM) + kh * DIM);
#pragma unroll
    for (int i = 0; i < 32; ++i) w[i] = Wp[i];
#pragma unroll
    for (int i = 0; i < 32; ++i)
        asm volatile("" : "+v"(w[i].x), "+v"(w[i].y), "+v"(w[i].z), "+v"(w[i].w));

    // ---- stage 16 concat rows ----
#pragma unroll
    for (int p = 0; p < 2; ++p) {
        const int idx  = p * 256 + tid;        // 0..511
        const int r    = idx >> 5;             // row 0..15
        const int c4   = idx & 31;             // float4 col 0..31
        *reinterpret_cast<float4*>(&tile[r * 256 + c4 * 4]) =
            *reinterpret_cast<const float4*>(h + (base + r) * DIM + c4 * 4);
        *reinterpret_cast<float4*>(&tile[r * 256 + DIM + c4 * 4]) =
            *reinterpret_cast<const float4*>(cbuf + (base + r) * DIM + c4 * 4);
    }
    __syncthreads();

    // ---- partial dots: 4 independent accumulators, wave-uniform LDS reads ----
#pragma unroll
    for (int n = 0; n < 16; ++n) {
        const float4* cp = reinterpret_cast<const float4*>(&tile[n * 256 + kh * DIM]);
        float s0 = 0.f, s1 = 0.f, s2 = 0.f, s3 = 0.f;
#pragma unroll
        for (int i = 0; i < 32; ++i) {
            const float4 cv = cp[i];
            s0 = fmaf(cv.x, w[i].x, s0);
            s1 = fmaf(cv.y, w[i].y, s1);
            s2 = fmaf(cv.z, w[i].z, s2);
            s3 = fmaf(cv.w, w[i].w, s3);
        }
        par[n * 256 + tid] = (s0 + s1) + (s2 + s3);
    }
    __syncthreads();

    // ---- reduce + L2 norm: group g handles nodes g*8..g*8+7 ----
    const int g = tid >> 7;                    // 0 or 1
    float bjArr[8];
#pragma unroll
    for (int m = 0; m < 8; ++m) {
        const int n = g * 8 + m;
        float bj = par[n * 256 + j] + par[n * 256 + DIM + j];
        bjArr[m] = bj;
        float sq = bj * bj;
#pragma unroll
        for (int off = 32; off > 0; off >>= 1) sq += __shfl_xor(sq, off);
        if ((tid & 63) == 0) red[n * 2 + (j >> 6)] = sq;
    }
    __syncthreads();

#pragma unroll
    for (int m = 0; m < 8; ++m) {
        const int n = g * 8 + m;
        const float nrm   = sqrtf(red[n * 2] + red[n * 2 + 1]);
        const float scale = 1.0f / fmaxf(nrm, 1e-12f);
        const float sn    = snorm[base + n];
        out[(base + n) * DIM + j] = fmaxf(bjArr[m] * scale, 0.0f) * sn;
    }
}

// ---------------- launcher ----------------

extern "C" void kernel_launch(void* const* d_in, const int* in_sizes, int n_in,
                              void* d_out, int out_size, void* d_ws, size_t ws_size,
                              hipStream_t stream) {
    const float* h     = (const float*)d_in[0];
    const float* snorm = (const float*)d_in[1];
    const float* W     = (const float*)d_in[2];
    const int*   src   = (const int*)d_in[3];
    const int*   dst   = (const int*)d_in[4];
    float*       out   = (float*)d_out;

    char* ws = (char*)d_ws;
    int* deg     = (int*)(ws + 0);          // 50000 ints
    int* cursor  = (int*)(ws + 200000);     // 50000 ints
    int* offsets = (int*)(ws + 400000);     // 50001 ints
    int* bsum    = (int*)(ws + 600416);     // 196 ints
    int* esrc    = (int*)(ws + 601216);     // 600000 ints

    hipMemsetAsync(ws, 0, 400000, stream);  // deg + cursor

    const int eblocks = (N_EDGES_C + 255) / 256;
    const int nblocks = (N_NODES_C + 255) / 256;   // 196
    count_kernel<<<eblocks, 256, 0, stream>>>(dst, deg, N_EDGES_C);
    scan1_kernel<<<nblocks, 256, 0, stream>>>(deg, offsets, bsum, N_NODES_C);
    scan2_kernel<<<1, 256, 0, stream>>>(bsum, nblocks);
    scan3_kernel<<<nblocks, 256, 0, stream>>>(offsets, bsum, N_NODES_C);
    fill_kernel<<<eblocks, 256, 0, stream>>>(src, dst, offsets, cursor, esrc, N_EDGES_C);

    // c lives in d_out; gemm_kernel overwrites it in place (per-block row-local)
    agg_kernel<<<(N_NODES_C + 3) / 4, 256, 0, stream>>>(h, offsets, esrc, out, N_NODES_C);
    gemm_kernel<<<N_NODES_C / 16, 256, 0, stream>>>(h, out, snorm, W, out, N_NODES_C);
}

// Round 4
// 167.884 us; speedup vs baseline: 2.8019x; 1.4776x over previous
//
#include <hip/hip_runtime.h>
#include <hip/hip_bf16.h>

#define N_NODES_C 50000
#define N_EDGES_C 600000
#define DIM 128

typedef __attribute__((ext_vector_type(8))) short short8;
typedef __attribute__((ext_vector_type(4))) float f32x4;

// ---------------- CSR build ----------------

__global__ void count_kernel(const int* __restrict__ dst, int* __restrict__ deg, int nE) {
    int e = blockIdx.x * blockDim.x + threadIdx.x;
    if (e < nE) atomicAdd(&deg[dst[e]], 1);
}

__global__ void scan1_kernel(const int* __restrict__ deg, int* __restrict__ offs,
                             int* __restrict__ bsum, int n) {
    __shared__ int buf[256];
    const int t = threadIdx.x;
    const int i = blockIdx.x * 256 + t;
    int v = (i < n) ? deg[i] : 0;
    buf[t] = v;
    __syncthreads();
    for (int off = 1; off < 256; off <<= 1) {
        int x = (t >= off) ? buf[t - off] : 0;
        __syncthreads();
        buf[t] += x;
        __syncthreads();
    }
    if (i < n) offs[i + 1] = buf[t];
    if (t == 255) bsum[blockIdx.x] = buf[255];
}

__global__ void scan2_kernel(int* __restrict__ bsum, int nb) {
    __shared__ int buf[256];
    const int t = threadIdx.x;
    int v = (t < nb) ? bsum[t] : 0;
    buf[t] = v;
    __syncthreads();
    for (int off = 1; off < 256; off <<= 1) {
        int x = (t >= off) ? buf[t - off] : 0;
        __syncthreads();
        buf[t] += x;
        __syncthreads();
    }
    if (t < nb) bsum[t] = (t == 0) ? 0 : buf[t - 1];
}

__global__ void scan3_kernel(int* __restrict__ offs, const int* __restrict__ bsum, int n) {
    const int i = blockIdx.x * 256 + threadIdx.x;
    if (i < n) offs[i + 1] += bsum[i >> 8];
    if (i == 0) offs[0] = 0;
}

__global__ void fill_kernel(const int* __restrict__ src, const int* __restrict__ dst,
                            const int* __restrict__ offsets, int* __restrict__ cursor,
                            int* __restrict__ esrc, int nE) {
    int e = blockIdx.x * blockDim.x + threadIdx.x;
    if (e < nE) {
        int d = dst[e];
        int pos = atomicAdd(&cursor[d], 1);
        esrc[offsets[d] + pos] = src[e];
    }
}

// ---------------- aggregation: one wave per node, no barriers ----------------

__global__ void agg_kernel(const float* __restrict__ h, const int* __restrict__ offsets,
                           const int* __restrict__ esrc, float* __restrict__ c, int nNodes) {
    const int tid  = threadIdx.x;
    const int lane = tid & 63;
    const int wid  = tid >> 6;
    const int node = blockIdx.x * 4 + wid;
    if (node >= nNodes) return;

    const int start = offsets[node];
    const int end   = offsets[node + 1];
    const int col4  = lane & 31;
    const int eh    = lane >> 5;

    float4 acc = {0.f, 0.f, 0.f, 0.f};
    for (int base = start; base < end; base += 64) {
        const int cnt = min(64, end - base);
        const int ev  = (lane < cnt) ? esrc[base + lane] : 0;
        for (int it = 0; 2 * it + eh < cnt; ++it) {
            const int s = __shfl(ev, 2 * it + eh);
            const float4 v = *reinterpret_cast<const float4*>(h + s * DIM + col4 * 4);
            acc.x += v.x; acc.y += v.y; acc.z += v.z; acc.w += v.w;
        }
    }
    acc.x += __shfl_xor(acc.x, 32);
    acc.y += __shfl_xor(acc.y, 32);
    acc.z += __shfl_xor(acc.z, 32);
    acc.w += __shfl_xor(acc.w, 32);

    if (lane < 32) {
        const int deg = end - start;
        const float inv = 1.0f / (float)(deg > 1 ? deg : 1);
        float4 o = {acc.x * inv, acc.y * inv, acc.z * inv, acc.w * inv};
        *reinterpret_cast<float4*>(c + node * DIM + col4 * 4) = o;
    }
}

// ---------------- MFMA GEMM + L2norm + relu + snorm ----------------
// 256 thr = 4 waves. Block = 64 rows. Wave w owns cols [32w, 32w+32).
// B (W rows, bf16) preloaded in 64 VGPRs; A (h|c fp32) converted on the fly.
// One barrier per block. C/D layout (m89): col=lane&15, row=(lane>>4)*4+reg.

__device__ inline unsigned short f2bf_u(float f) {
    union { __hip_bfloat16 b; unsigned short u; } cv;
    cv.b = __float2bfloat16(f);
    return cv.u;
}

__device__ inline short8 cvt8(const float* p) {
    const float4 lo = *reinterpret_cast<const float4*>(p);
    const float4 hi = *reinterpret_cast<const float4*>(p + 4);
    short8 r;
    r[0] = (short)f2bf_u(lo.x); r[1] = (short)f2bf_u(lo.y);
    r[2] = (short)f2bf_u(lo.z); r[3] = (short)f2bf_u(lo.w);
    r[4] = (short)f2bf_u(hi.x); r[5] = (short)f2bf_u(hi.y);
    r[6] = (short)f2bf_u(hi.z); r[7] = (short)f2bf_u(hi.w);
    return r;
}

__launch_bounds__(256)
__global__ void gemm_kernel(const float* __restrict__ h, const float* cbuf,
                            const float* __restrict__ snorm, const float* __restrict__ W,
                            float* out, int nNodes) {
    __shared__ float rowsq[4][16][4];

    const int tid  = threadIdx.x;
    const int wid  = tid >> 6;
    const int lane = tid & 63;
    const int lr   = lane & 15;   // A-row / B-col / C-col within tile
    const int lk   = lane >> 4;   // k-block (0..3)
    const int base = blockIdx.x * 64;

    // ---- preload B fragments: W[(2wid+t)*16+lr][ks*32 + lk*8 ..+7] ----
    short8 b[2][8];
#pragma unroll
    for (int t = 0; t < 2; ++t) {
        const int wrow = (wid * 2 + t) * 16 + lr;
#pragma unroll
        for (int ks = 0; ks < 8; ++ks)
            b[t][ks] = cvt8(W + wrow * 256 + ks * 32 + lk * 8);
    }

    f32x4 acc[4][2];
#pragma unroll
    for (int rt = 0; rt < 4; ++rt) {
        acc[rt][0] = (f32x4)(0.f);
        acc[rt][1] = (f32x4)(0.f);
        int arow = base + rt * 16 + lr;
        arow = (arow < nNodes) ? arow : (nNodes - 1);
        const float* hp = h    + arow * DIM + lk * 8;
        const float* cp = cbuf + arow * DIM + lk * 8;
#pragma unroll
        for (int ks = 0; ks < 4; ++ks) {
            const short8 a = cvt8(hp + ks * 32);
            acc[rt][0] = __builtin_amdgcn_mfma_f32_16x16x32_bf16(a, b[0][ks], acc[rt][0], 0, 0, 0);
            acc[rt][1] = __builtin_amdgcn_mfma_f32_16x16x32_bf16(a, b[1][ks], acc[rt][1], 0, 0, 0);
        }
#pragma unroll
        for (int ks = 0; ks < 4; ++ks) {
            const short8 a = cvt8(cp + ks * 32);
            acc[rt][0] = __builtin_amdgcn_mfma_f32_16x16x32_bf16(a, b[0][ks + 4], acc[rt][0], 0, 0, 0);
            acc[rt][1] = __builtin_amdgcn_mfma_f32_16x16x32_bf16(a, b[1][ks + 4], acc[rt][1], 0, 0, 0);
        }
        // per-row sum of squares over this wave's 32 cols
#pragma unroll
        for (int r = 0; r < 4; ++r) {
            float sq = acc[rt][0][r] * acc[rt][0][r] + acc[rt][1][r] * acc[rt][1][r];
            sq += __shfl_xor(sq, 1);
            sq += __shfl_xor(sq, 2);
            sq += __shfl_xor(sq, 4);
            sq += __shfl_xor(sq, 8);
            if (lr == 0) rowsq[rt][lk * 4 + r][wid] = sq;
        }
    }
    __syncthreads();

    // ---- normalize + relu + snorm + store ----
#pragma unroll
    for (int rt = 0; rt < 4; ++rt) {
#pragma unroll
        for (int r = 0; r < 4; ++r) {
            const int row16 = lk * 4 + r;
            const int node  = base + rt * 16 + row16;
            if (node < nNodes) {
                const float nsq = rowsq[rt][row16][0] + rowsq[rt][row16][1]
                                + rowsq[rt][row16][2] + rowsq[rt][row16][3];
                const float nrm   = sqrtf(nsq);
                const float scale = 1.0f / fmaxf(nrm, 1e-12f);
                const float sn    = snorm[node];
#pragma unroll
                for (int t = 0; t < 2; ++t) {
                    const int col = (wid * 2 + t) * 16 + lr;
                    out[node * DIM + col] = fmaxf(acc[rt][t][r] * scale, 0.f) * sn;
                }
            }
        }
    }
}

// ---------------- launcher ----------------

extern "C" void kernel_launch(void* const* d_in, const int* in_sizes, int n_in,
                              void* d_out, int out_size, void* d_ws, size_t ws_size,
                              hipStream_t stream) {
    const float* h     = (const float*)d_in[0];
    const float* snorm = (const float*)d_in[1];
    const float* W     = (const float*)d_in[2];
    const int*   src   = (const int*)d_in[3];
    const int*   dst   = (const int*)d_in[4];
    float*       out   = (float*)d_out;

    char* ws = (char*)d_ws;
    int* deg     = (int*)(ws + 0);          // 50000 ints
    int* cursor  = (int*)(ws + 200000);     // 50000 ints
    int* offsets = (int*)(ws + 400000);     // 50001 ints
    int* bsum    = (int*)(ws + 600416);     // 196 ints
    int* esrc    = (int*)(ws + 601216);     // 600000 ints

    hipMemsetAsync(ws, 0, 400000, stream);  // deg + cursor

    const int eblocks = (N_EDGES_C + 255) / 256;
    const int nblocks = (N_NODES_C + 255) / 256;   // 196
    count_kernel<<<eblocks, 256, 0, stream>>>(dst, deg, N_EDGES_C);
    scan1_kernel<<<nblocks, 256, 0, stream>>>(deg, offsets, bsum, N_NODES_C);
    scan2_kernel<<<1, 256, 0, stream>>>(bsum, nblocks);
    scan3_kernel<<<nblocks, 256, 0, stream>>>(offsets, bsum, N_NODES_C);
    fill_kernel<<<eblocks, 256, 0, stream>>>(src, dst, offsets, cursor, esrc, N_EDGES_C);

    // c (fp32) lives in d_out; gemm reads its own 64 rows then overwrites them
    agg_kernel<<<(N_NODES_C + 3) / 4, 256, 0, stream>>>(h, offsets, esrc, out, N_NODES_C);
    gemm_kernel<<<(N_NODES_C + 63) / 64, 256, 0, stream>>>(h, out, snorm, W, out, N_NODES_C);
}

// Round 5
// 145.579 us; speedup vs baseline: 3.2312x; 1.1532x over previous
//
#include <hip/hip_runtime.h>
#include <hip/hip_bf16.h>

#define N_NODES_C 50000
#define N_EDGES_C 600000
#define DIM 128

typedef __attribute__((ext_vector_type(8))) short short8;
typedef __attribute__((ext_vector_type(4))) float f32x4;

__device__ inline unsigned short f2bf_u(float f) {
    union { __hip_bfloat16 b; unsigned short u; } cv;
    cv.b = __float2bfloat16(f);
    return cv.u;
}

// ---------------- CSR build ----------------

__global__ void count_kernel(const int* __restrict__ dst, int* __restrict__ deg, int nE) {
    int e = blockIdx.x * blockDim.x + threadIdx.x;
    if (e < nE) atomicAdd(&deg[dst[e]], 1);
}

__global__ void scan1_kernel(const int* __restrict__ deg, int* __restrict__ offs,
                             int* __restrict__ bsum, int n) {
    __shared__ int buf[256];
    const int t = threadIdx.x;
    const int i = blockIdx.x * 256 + t;
    int v = (i < n) ? deg[i] : 0;
    buf[t] = v;
    __syncthreads();
    for (int off = 1; off < 256; off <<= 1) {
        int x = (t >= off) ? buf[t - off] : 0;
        __syncthreads();
        buf[t] += x;
        __syncthreads();
    }
    if (i < n) offs[i + 1] = buf[t];
    if (t == 255) bsum[blockIdx.x] = buf[255];
}

__global__ void scan2_kernel(int* __restrict__ bsum, int nb) {
    __shared__ int buf[256];
    const int t = threadIdx.x;
    int v = (t < nb) ? bsum[t] : 0;
    buf[t] = v;
    __syncthreads();
    for (int off = 1; off < 256; off <<= 1) {
        int x = (t >= off) ? buf[t - off] : 0;
        __syncthreads();
        buf[t] += x;
        __syncthreads();
    }
    if (t < nb) bsum[t] = (t == 0) ? 0 : buf[t - 1];
}

__global__ void scan3_kernel(int* __restrict__ offs, const int* __restrict__ bsum, int n) {
    const int i = blockIdx.x * 256 + threadIdx.x;
    if (i < n) offs[i + 1] += bsum[i >> 8];
    if (i == 0) offs[0] = 0;
}

__global__ void fill_kernel(const int* __restrict__ src, const int* __restrict__ dst,
                            const int* __restrict__ offsets, int* __restrict__ cursor,
                            int* __restrict__ esrc, int nE) {
    int e = blockIdx.x * blockDim.x + threadIdx.x;
    if (e < nE) {
        int d = dst[e];
        int pos = atomicAdd(&cursor[d], 1);
        esrc[offsets[d] + pos] = src[e];
    }
}

// ---------------- fp32 -> bf16 streaming convert ----------------

__global__ void f2bf_kernel(const float4* __restrict__ in, ushort4* __restrict__ out, int n4) {
    int i = blockIdx.x * blockDim.x + threadIdx.x;
    const int stride = gridDim.x * blockDim.x;
    for (; i < n4; i += stride) {
        const float4 v = in[i];
        ushort4 o;
        o.x = f2bf_u(v.x); o.y = f2bf_u(v.y); o.z = f2bf_u(v.z); o.w = f2bf_u(v.w);
        out[i] = o;
    }
}

// ---------------- aggregation (bf16 rows): one wave per node ----------------
// Half-wave (32 lanes x 8B = 256B row) per edge; fp32 accumulate; bf16 c out.

__global__ void agg_bf_kernel(const unsigned short* __restrict__ hb,
                              const int* __restrict__ offsets,
                              const int* __restrict__ esrc,
                              unsigned short* __restrict__ cb, int nNodes) {
    const int tid  = threadIdx.x;
    const int lane = tid & 63;
    const int wid  = tid >> 6;
    const int node = blockIdx.x * 4 + wid;
    if (node >= nNodes) return;

    const int start = offsets[node];
    const int end   = offsets[node + 1];
    const int col4  = lane & 31;   // 4 bf16 (8B) per lane
    const int eh    = lane >> 5;   // even/odd edge split

    float4 acc = {0.f, 0.f, 0.f, 0.f};
    for (int base = start; base < end; base += 64) {
        const int cnt = min(64, end - base);
        const int ev  = (lane < cnt) ? esrc[base + lane] : 0;
        for (int it = 0; 2 * it + eh < cnt; ++it) {
            const int s = __shfl(ev, 2 * it + eh);
            const uint2 u = *reinterpret_cast<const uint2*>(hb + s * DIM + col4 * 4);
            acc.x += __uint_as_float(u.x << 16);
            acc.y += __uint_as_float(u.x & 0xffff0000u);
            acc.z += __uint_as_float(u.y << 16);
            acc.w += __uint_as_float(u.y & 0xffff0000u);
        }
    }
    acc.x += __shfl_xor(acc.x, 32);
    acc.y += __shfl_xor(acc.y, 32);
    acc.z += __shfl_xor(acc.z, 32);
    acc.w += __shfl_xor(acc.w, 32);

    if (lane < 32) {
        const int deg = end - start;
        const float inv = 1.0f / (float)(deg > 1 ? deg : 1);
        ushort4 o;
        o.x = f2bf_u(acc.x * inv);
        o.y = f2bf_u(acc.y * inv);
        o.z = f2bf_u(acc.z * inv);
        o.w = f2bf_u(acc.w * inv);
        *reinterpret_cast<ushort4*>(cb + node * DIM + col4 * 4) = o;
    }
}

// ---------------- MFMA GEMM (bf16 operands) + L2norm + relu + snorm ----------
// 256 thr = 4 waves, 32 rows/block (1563 blocks). Wave w owns cols [32w,32w+32).
// B pinned in 64 VGPRs (direct 16B loads); A frags batch-loaded per row-tile.
// C/D layout (m89): col=lane&15, row=(lane>>4)*4+reg.

__launch_bounds__(256, 3)
__global__ void gemm_bf_kernel(const unsigned short* __restrict__ hb,
                               const unsigned short* __restrict__ cb,
                               const float* __restrict__ snorm,
                               const unsigned short* __restrict__ Wb,
                               float* __restrict__ out, int nNodes) {
    __shared__ float rowsq[2][16][4];

    const int tid  = threadIdx.x;
    const int wid  = tid >> 6;
    const int lane = tid & 63;
    const int lr   = lane & 15;
    const int lk   = lane >> 4;
    const int base = blockIdx.x * 32;

    // B fragments: W[(2wid+t)*16+lr][ks*32 + lk*8 ..+7], direct bf16 loads
    short8 b[2][8];
#pragma unroll
    for (int t = 0; t < 2; ++t) {
        const int wrow = (wid * 2 + t) * 16 + lr;
#pragma unroll
        for (int ks = 0; ks < 8; ++ks)
            b[t][ks] = *reinterpret_cast<const short8*>(Wb + wrow * 256 + ks * 32 + lk * 8);
    }
#pragma unroll
    for (int t = 0; t < 2; ++t)
#pragma unroll
        for (int ks = 0; ks < 8; ++ks)
            asm volatile("" : "+v"(b[t][ks]));

    f32x4 acc[2][2];
#pragma unroll
    for (int rt = 0; rt < 2; ++rt) {
        acc[rt][0] = (f32x4)(0.f);
        acc[rt][1] = (f32x4)(0.f);
        int arow = base + rt * 16 + lr;
        arow = (arow < nNodes) ? arow : (nNodes - 1);
        const unsigned short* hp = hb + arow * DIM + lk * 8;
        const unsigned short* cp = cb + arow * DIM + lk * 8;

        short8 a[8];
#pragma unroll
        for (int ks = 0; ks < 4; ++ks) {
            a[ks]     = *reinterpret_cast<const short8*>(hp + ks * 32);
            a[ks + 4] = *reinterpret_cast<const short8*>(cp + ks * 32);
        }
#pragma unroll
        for (int ks = 0; ks < 8; ++ks) {
            acc[rt][0] = __builtin_amdgcn_mfma_f32_16x16x32_bf16(a[ks], b[0][ks], acc[rt][0], 0, 0, 0);
            acc[rt][1] = __builtin_amdgcn_mfma_f32_16x16x32_bf16(a[ks], b[1][ks], acc[rt][1], 0, 0, 0);
        }
#pragma unroll
        for (int r = 0; r < 4; ++r) {
            float sq = acc[rt][0][r] * acc[rt][0][r] + acc[rt][1][r] * acc[rt][1][r];
            sq += __shfl_xor(sq, 1);
            sq += __shfl_xor(sq, 2);
            sq += __shfl_xor(sq, 4);
            sq += __shfl_xor(sq, 8);
            if (lr == 0) rowsq[rt][lk * 4 + r][wid] = sq;
        }
    }
    __syncthreads();

#pragma unroll
    for (int rt = 0; rt < 2; ++rt) {
#pragma unroll
        for (int r = 0; r < 4; ++r) {
            const int row16 = lk * 4 + r;
            const int node  = base + rt * 16 + row16;
            if (node < nNodes) {
                const float nsq = rowsq[rt][row16][0] + rowsq[rt][row16][1]
                                + rowsq[rt][row16][2] + rowsq[rt][row16][3];
                const float scale = 1.0f / fmaxf(sqrtf(nsq), 1e-12f);
                const float sn    = snorm[node];
#pragma unroll
                for (int t = 0; t < 2; ++t) {
                    const int col = (wid * 2 + t) * 16 + lr;
                    out[node * DIM + col] = fmaxf(acc[rt][t][r] * scale, 0.f) * sn;
                }
            }
        }
    }
}

// ---------------- fallback fp32 path (if ws too small) ----------------

__global__ void agg_kernel(const float* __restrict__ h, const int* __restrict__ offsets,
                           const int* __restrict__ esrc, float* __restrict__ c, int nNodes) {
    const int tid  = threadIdx.x;
    const int lane = tid & 63;
    const int wid  = tid >> 6;
    const int node = blockIdx.x * 4 + wid;
    if (node >= nNodes) return;
    const int start = offsets[node];
    const int end   = offsets[node + 1];
    const int col4  = lane & 31;
    const int eh    = lane >> 5;
    float4 acc = {0.f, 0.f, 0.f, 0.f};
    for (int base = start; base < end; base += 64) {
        const int cnt = min(64, end - base);
        const int ev  = (lane < cnt) ? esrc[base + lane] : 0;
        for (int it = 0; 2 * it + eh < cnt; ++it) {
            const int s = __shfl(ev, 2 * it + eh);
            const float4 v = *reinterpret_cast<const float4*>(h + s * DIM + col4 * 4);
            acc.x += v.x; acc.y += v.y; acc.z += v.z; acc.w += v.w;
        }
    }
    acc.x += __shfl_xor(acc.x, 32);
    acc.y += __shfl_xor(acc.y, 32);
    acc.z += __shfl_xor(acc.z, 32);
    acc.w += __shfl_xor(acc.w, 32);
    if (lane < 32) {
        const int deg = end - start;
        const float inv = 1.0f / (float)(deg > 1 ? deg : 1);
        float4 o = {acc.x * inv, acc.y * inv, acc.z * inv, acc.w * inv};
        *reinterpret_cast<float4*>(c + node * DIM + col4 * 4) = o;
    }
}

__device__ inline short8 cvt8(const float* p) {
    const float4 lo = *reinterpret_cast<const float4*>(p);
    const float4 hi = *reinterpret_cast<const float4*>(p + 4);
    short8 r;
    r[0] = (short)f2bf_u(lo.x); r[1] = (short)f2bf_u(lo.y);
    r[2] = (short)f2bf_u(lo.z); r[3] = (short)f2bf_u(lo.w);
    r[4] = (short)f2bf_u(hi.x); r[5] = (short)f2bf_u(hi.y);
    r[6] = (short)f2bf_u(hi.z); r[7] = (short)f2bf_u(hi.w);
    return r;
}

__launch_bounds__(256)
__global__ void gemm_kernel(const float* __restrict__ h, const float* cbuf,
                            const float* __restrict__ snorm, const float* __restrict__ W,
                            float* out, int nNodes) {
    __shared__ float rowsq[4][16][4];
    const int tid  = threadIdx.x;
    const int wid  = tid >> 6;
    const int lane = tid & 63;
    const int lr   = lane & 15;
    const int lk   = lane >> 4;
    const int base = blockIdx.x * 64;
    short8 b[2][8];
#pragma unroll
    for (int t = 0; t < 2; ++t) {
        const int wrow = (wid * 2 + t) * 16 + lr;
#pragma unroll
        for (int ks = 0; ks < 8; ++ks)
            b[t][ks] = cvt8(W + wrow * 256 + ks * 32 + lk * 8);
    }
    f32x4 acc[4][2];
#pragma unroll
    for (int rt = 0; rt < 4; ++rt) {
        acc[rt][0] = (f32x4)(0.f);
        acc[rt][1] = (f32x4)(0.f);
        int arow = base + rt * 16 + lr;
        arow = (arow < nNodes) ? arow : (nNodes - 1);
        const float* hp = h    + arow * DIM + lk * 8;
        const float* cp = cbuf + arow * DIM + lk * 8;
#pragma unroll
        for (int ks = 0; ks < 4; ++ks) {
            const short8 a = cvt8(hp + ks * 32);
            acc[rt][0] = __builtin_amdgcn_mfma_f32_16x16x32_bf16(a, b[0][ks], acc[rt][0], 0, 0, 0);
            acc[rt][1] = __builtin_amdgcn_mfma_f32_16x16x32_bf16(a, b[1][ks], acc[rt][1], 0, 0, 0);
        }
#pragma unroll
        for (int ks = 0; ks < 4; ++ks) {
            const short8 a = cvt8(cp + ks * 32);
            acc[rt][0] = __builtin_amdgcn_mfma_f32_16x16x32_bf16(a, b[0][ks + 4], acc[rt][0], 0, 0, 0);
            acc[rt][1] = __builtin_amdgcn_mfma_f32_16x16x32_bf16(a, b[1][ks + 4], acc[rt][1], 0, 0, 0);
        }
#pragma unroll
        for (int r = 0; r < 4; ++r) {
            float sq = acc[rt][0][r] * acc[rt][0][r] + acc[rt][1][r] * acc[rt][1][r];
            sq += __shfl_xor(sq, 1);
            sq += __shfl_xor(sq, 2);
            sq += __shfl_xor(sq, 4);
            sq += __shfl_xor(sq, 8);
            if (lr == 0) rowsq[rt][lk * 4 + r][wid] = sq;
        }
    }
    __syncthreads();
#pragma unroll
    for (int rt = 0; rt < 4; ++rt) {
#pragma unroll
        for (int r = 0; r < 4; ++r) {
            const int row16 = lk * 4 + r;
            const int node  = base + rt * 16 + row16;
            if (node < nNodes) {
                const float nsq = rowsq[rt][row16][0] + rowsq[rt][row16][1]
                                + rowsq[rt][row16][2] + rowsq[rt][row16][3];
                const float scale = 1.0f / fmaxf(sqrtf(nsq), 1e-12f);
                const float sn    = snorm[node];
#pragma unroll
                for (int t = 0; t < 2; ++t) {
                    const int col = (wid * 2 + t) * 16 + lr;
                    out[node * DIM + col] = fmaxf(acc[rt][t][r] * scale, 0.f) * sn;
                }
            }
        }
    }
}

// ---------------- launcher ----------------

extern "C" void kernel_launch(void* const* d_in, const int* in_sizes, int n_in,
                              void* d_out, int out_size, void* d_ws, size_t ws_size,
                              hipStream_t stream) {
    const float* h     = (const float*)d_in[0];
    const float* snorm = (const float*)d_in[1];
    const float* W     = (const float*)d_in[2];
    const int*   src   = (const int*)d_in[3];
    const int*   dst   = (const int*)d_in[4];
    float*       out   = (float*)d_out;

    char* ws = (char*)d_ws;
    int* deg     = (int*)(ws + 0);              // 50000 ints
    int* cursor  = (int*)(ws + 200000);         // 50000 ints
    int* offsets = (int*)(ws + 400000);         // 50001 ints
    int* bsum    = (int*)(ws + 600416);         // 196 ints
    int* esrc    = (int*)(ws + 601216);         // 600000 ints -> ends 3001216
    unsigned short* hb = (unsigned short*)(ws + 3001344);    // 12.8 MB
    unsigned short* cb = (unsigned short*)(ws + 15801344);   // 12.8 MB
    unsigned short* Wb = (unsigned short*)(ws + 28601344);   // 64 KB
    const size_t NEED = 28666880;

    hipMemsetAsync(ws, 0, 400000, stream);  // deg + cursor

    const int eblocks = (N_EDGES_C + 255) / 256;
    const int nblocks = (N_NODES_C + 255) / 256;   // 196
    count_kernel<<<eblocks, 256, 0, stream>>>(dst, deg, N_EDGES_C);
    scan1_kernel<<<nblocks, 256, 0, stream>>>(deg, offsets, bsum, N_NODES_C);
    scan2_kernel<<<1, 256, 0, stream>>>(bsum, nblocks);
    scan3_kernel<<<nblocks, 256, 0, stream>>>(offsets, bsum, N_NODES_C);
    fill_kernel<<<eblocks, 256, 0, stream>>>(src, dst, offsets, cursor, esrc, N_EDGES_C);

    if (ws_size >= NEED) {
        f2bf_kernel<<<2048, 256, 0, stream>>>((const float4*)h, (ushort4*)hb, N_NODES_C * DIM / 4);
        f2bf_kernel<<<32, 256, 0, stream>>>((const float4*)W, (ushort4*)Wb, DIM * 2 * DIM / 4);
        agg_bf_kernel<<<(N_NODES_C + 3) / 4, 256, 0, stream>>>(hb, offsets, esrc, cb, N_NODES_C);
        gemm_bf_kernel<<<(N_NODES_C + 31) / 32, 256, 0, stream>>>(hb, cb, snorm, Wb, out, N_NODES_C);
    } else {
        // fp32 fallback: c lives in d_out; gemm overwrites its own rows in place
        agg_kernel<<<(N_NODES_C + 3) / 4, 256, 0, stream>>>(h, offsets, esrc, out, N_NODES_C);
        gemm_kernel<<<(N_NODES_C + 63) / 64, 256, 0, stream>>>(h, out, snorm, W, out, N_NODES_C);
    }
}

// Round 6
// 142.200 us; speedup vs baseline: 3.3080x; 1.0238x over previous
//
#include <hip/hip_runtime.h>
#include <hip/hip_bf16.h>

#define N_NODES_C 50000
#define N_EDGES_C 600000
#define DIM 128

typedef __attribute__((ext_vector_type(8))) short short8;
typedef __attribute__((ext_vector_type(4))) float f32x4;

__device__ inline unsigned short f2bf_u(float f) {
    union { __hip_bfloat16 b; unsigned short u; } cv;
    cv.b = __float2bfloat16(f);
    return cv.u;
}

// ---------------- prep: zero deg + convert W to bf16 ----------------
// blocks [0,49): zero 50000 ints of deg; blocks [49,81): convert 8192 float4 of W.

__global__ void prep_kernel(int4* __restrict__ deg4, const float4* __restrict__ W4,
                            ushort4* __restrict__ Wb4, int doCvt) {
    const int b = blockIdx.x;
    const int t = threadIdx.x;
    if (b < 49) {
        const int i = b * 256 + t;
        if (i < 12500) deg4[i] = make_int4(0, 0, 0, 0);
    } else if (doCvt) {
        const int i = (b - 49) * 256 + t;
        if (i < 8192) {
            const float4 v = W4[i];
            ushort4 o;
            o.x = f2bf_u(v.x); o.y = f2bf_u(v.y); o.z = f2bf_u(v.z); o.w = f2bf_u(v.w);
            Wb4[i] = o;
        }
    }
}

// ---------------- count degrees + convert h to bf16 ----------------
// blocks [0,2344): count; blocks [2344,2344+2048): grid-stride convert h.

#define EBLOCKS 2344
#define HCVT_BLOCKS 2048

__global__ void count_h_kernel(const int* __restrict__ dst, int* __restrict__ deg,
                               const float4* __restrict__ h4, ushort4* __restrict__ hb4,
                               int doCvt) {
    const int b = blockIdx.x;
    const int t = threadIdx.x;
    if (b < EBLOCKS) {
        const int e = b * 256 + t;
        if (e < N_EDGES_C) atomicAdd(&deg[dst[e]], 1);
    } else if (doCvt) {
        const int n4 = N_NODES_C * DIM / 4;   // 1.6M float4
        int i = (b - EBLOCKS) * 256 + t;
        const int stride = HCVT_BLOCKS * 256;
        for (; i < n4; i += stride) {
            const float4 v = h4[i];
            ushort4 o;
            o.x = f2bf_u(v.x); o.y = f2bf_u(v.y); o.z = f2bf_u(v.z); o.w = f2bf_u(v.w);
            hb4[i] = o;
        }
    }
}

// ---------------- scans ----------------

__global__ void scan1_kernel(const int* __restrict__ deg, int* __restrict__ offs,
                             int* __restrict__ bsum, int n) {
    __shared__ int buf[256];
    const int t = threadIdx.x;
    const int i = blockIdx.x * 256 + t;
    int v = (i < n) ? deg[i] : 0;
    buf[t] = v;
    __syncthreads();
    for (int off = 1; off < 256; off <<= 1) {
        int x = (t >= off) ? buf[t - off] : 0;
        __syncthreads();
        buf[t] += x;
        __syncthreads();
    }
    if (i < n) offs[i + 1] = buf[t];
    if (t == 255) bsum[blockIdx.x] = buf[255];
}

__global__ void scan2_kernel(int* __restrict__ bsum, int nb) {
    __shared__ int buf[256];
    const int t = threadIdx.x;
    int v = (t < nb) ? bsum[t] : 0;
    buf[t] = v;
    __syncthreads();
    for (int off = 1; off < 256; off <<= 1) {
        int x = (t >= off) ? buf[t - off] : 0;
        __syncthreads();
        buf[t] += x;
        __syncthreads();
    }
    if (t < nb) bsum[t] = (t == 0) ? 0 : buf[t - 1];
}

// finalize offsets AND initialize cursor[k] = offsets[k]
__global__ void scan3_kernel(int* __restrict__ offs, const int* __restrict__ bsum,
                             int* __restrict__ cursor, int n) {
    const int i = blockIdx.x * 256 + threadIdx.x;
    if (i < n) {
        const int v = offs[i + 1] + bsum[i >> 8];
        offs[i + 1]   = v;
        cursor[i + 1] = v;
    }
    if (i == 0) { offs[0] = 0; cursor[0] = 0; }
}

__global__ void fill_kernel(const int* __restrict__ src, const int* __restrict__ dst,
                            int* __restrict__ cursor, int* __restrict__ esrc, int nE) {
    int e = blockIdx.x * blockDim.x + threadIdx.x;
    if (e < nE) {
        const int pos = atomicAdd(&cursor[dst[e]], 1);   // absolute slot
        esrc[pos] = src[e];
    }
}

// ---------------- aggregation (bf16 rows): one wave per node ----------------

__global__ void agg_bf_kernel(const unsigned short* __restrict__ hb,
                              const int* __restrict__ offsets,
                              const int* __restrict__ esrc,
                              unsigned short* __restrict__ cb, int nNodes) {
    const int tid  = threadIdx.x;
    const int lane = tid & 63;
    const int wid  = tid >> 6;
    const int node = blockIdx.x * 4 + wid;
    if (node >= nNodes) return;

    const int start = offsets[node];
    const int end   = offsets[node + 1];
    const int col4  = lane & 31;
    const int eh    = lane >> 5;

    float4 acc = {0.f, 0.f, 0.f, 0.f};
    for (int base = start; base < end; base += 64) {
        const int cnt = min(64, end - base);
        const int ev  = (lane < cnt) ? esrc[base + lane] : 0;
        for (int it = 0; 2 * it + eh < cnt; ++it) {
            const int s = __shfl(ev, 2 * it + eh);
            const uint2 u = *reinterpret_cast<const uint2*>(hb + s * DIM + col4 * 4);
            acc.x += __uint_as_float(u.x << 16);
            acc.y += __uint_as_float(u.x & 0xffff0000u);
            acc.z += __uint_as_float(u.y << 16);
            acc.w += __uint_as_float(u.y & 0xffff0000u);
        }
    }
    acc.x += __shfl_xor(acc.x, 32);
    acc.y += __shfl_xor(acc.y, 32);
    acc.z += __shfl_xor(acc.z, 32);
    acc.w += __shfl_xor(acc.w, 32);

    if (lane < 32) {
        const int deg = end - start;
        const float inv = 1.0f / (float)(deg > 1 ? deg : 1);
        ushort4 o;
        o.x = f2bf_u(acc.x * inv);
        o.y = f2bf_u(acc.y * inv);
        o.z = f2bf_u(acc.z * inv);
        o.w = f2bf_u(acc.w * inv);
        *reinterpret_cast<ushort4*>(cb + node * DIM + col4 * 4) = o;
    }
}

// ---------------- MFMA GEMM (bf16) + L2norm + relu + snorm ----------------

__launch_bounds__(256, 3)
__global__ void gemm_bf_kernel(const unsigned short* __restrict__ hb,
                               const unsigned short* __restrict__ cb,
                               const float* __restrict__ snorm,
                               const unsigned short* __restrict__ Wb,
                               float* __restrict__ out, int nNodes) {
    __shared__ float rowsq[2][16][4];

    const int tid  = threadIdx.x;
    const int wid  = tid >> 6;
    const int lane = tid & 63;
    const int lr   = lane & 15;
    const int lk   = lane >> 4;
    const int base = blockIdx.x * 32;

    short8 b[2][8];
#pragma unroll
    for (int t = 0; t < 2; ++t) {
        const int wrow = (wid * 2 + t) * 16 + lr;
#pragma unroll
        for (int ks = 0; ks < 8; ++ks)
            b[t][ks] = *reinterpret_cast<const short8*>(Wb + wrow * 256 + ks * 32 + lk * 8);
    }
#pragma unroll
    for (int t = 0; t < 2; ++t)
#pragma unroll
        for (int ks = 0; ks < 8; ++ks)
            asm volatile("" : "+v"(b[t][ks]));

    f32x4 acc[2][2];
#pragma unroll
    for (int rt = 0; rt < 2; ++rt) {
        acc[rt][0] = (f32x4)(0.f);
        acc[rt][1] = (f32x4)(0.f);
        int arow = base + rt * 16 + lr;
        arow = (arow < nNodes) ? arow : (nNodes - 1);
        const unsigned short* hp = hb + arow * DIM + lk * 8;
        const unsigned short* cp = cb + arow * DIM + lk * 8;

        short8 a[8];
#pragma unroll
        for (int ks = 0; ks < 4; ++ks) {
            a[ks]     = *reinterpret_cast<const short8*>(hp + ks * 32);
            a[ks + 4] = *reinterpret_cast<const short8*>(cp + ks * 32);
        }
#pragma unroll
        for (int ks = 0; ks < 8; ++ks) {
            acc[rt][0] = __builtin_amdgcn_mfma_f32_16x16x32_bf16(a[ks], b[0][ks], acc[rt][0], 0, 0, 0);
            acc[rt][1] = __builtin_amdgcn_mfma_f32_16x16x32_bf16(a[ks], b[1][ks], acc[rt][1], 0, 0, 0);
        }
#pragma unroll
        for (int r = 0; r < 4; ++r) {
            float sq = acc[rt][0][r] * acc[rt][0][r] + acc[rt][1][r] * acc[rt][1][r];
            sq += __shfl_xor(sq, 1);
            sq += __shfl_xor(sq, 2);
            sq += __shfl_xor(sq, 4);
            sq += __shfl_xor(sq, 8);
            if (lr == 0) rowsq[rt][lk * 4 + r][wid] = sq;
        }
    }
    __syncthreads();

#pragma unroll
    for (int rt = 0; rt < 2; ++rt) {
#pragma unroll
        for (int r = 0; r < 4; ++r) {
            const int row16 = lk * 4 + r;
            const int node  = base + rt * 16 + row16;
            if (node < nNodes) {
                const float nsq = rowsq[rt][row16][0] + rowsq[rt][row16][1]
                                + rowsq[rt][row16][2] + rowsq[rt][row16][3];
                const float scale = 1.0f / fmaxf(sqrtf(nsq), 1e-12f);
                const float sn    = snorm[node];
#pragma unroll
                for (int t = 0; t < 2; ++t) {
                    const int col = (wid * 2 + t) * 16 + lr;
                    out[node * DIM + col] = fmaxf(acc[rt][t][r] * scale, 0.f) * sn;
                }
            }
        }
    }
}

// ---------------- fp32 fallback (ws too small) ----------------

__global__ void agg_kernel(const float* __restrict__ h, const int* __restrict__ offsets,
                           const int* __restrict__ esrc, float* __restrict__ c, int nNodes) {
    const int tid  = threadIdx.x;
    const int lane = tid & 63;
    const int wid  = tid >> 6;
    const int node = blockIdx.x * 4 + wid;
    if (node >= nNodes) return;
    const int start = offsets[node];
    const int end   = offsets[node + 1];
    const int col4  = lane & 31;
    const int eh    = lane >> 5;
    float4 acc = {0.f, 0.f, 0.f, 0.f};
    for (int base = start; base < end; base += 64) {
        const int cnt = min(64, end - base);
        const int ev  = (lane < cnt) ? esrc[base + lane] : 0;
        for (int it = 0; 2 * it + eh < cnt; ++it) {
            const int s = __shfl(ev, 2 * it + eh);
            const float4 v = *reinterpret_cast<const float4*>(h + s * DIM + col4 * 4);
            acc.x += v.x; acc.y += v.y; acc.z += v.z; acc.w += v.w;
        }
    }
    acc.x += __shfl_xor(acc.x, 32);
    acc.y += __shfl_xor(acc.y, 32);
    acc.z += __shfl_xor(acc.z, 32);
    acc.w += __shfl_xor(acc.w, 32);
    if (lane < 32) {
        const int deg = end - start;
        const float inv = 1.0f / (float)(deg > 1 ? deg : 1);
        float4 o = {acc.x * inv, acc.y * inv, acc.z * inv, acc.w * inv};
        *reinterpret_cast<float4*>(c + node * DIM + col4 * 4) = o;
    }
}

__device__ inline short8 cvt8(const float* p) {
    const float4 lo = *reinterpret_cast<const float4*>(p);
    const float4 hi = *reinterpret_cast<const float4*>(p + 4);
    short8 r;
    r[0] = (short)f2bf_u(lo.x); r[1] = (short)f2bf_u(lo.y);
    r[2] = (short)f2bf_u(lo.z); r[3] = (short)f2bf_u(lo.w);
    r[4] = (short)f2bf_u(hi.x); r[5] = (short)f2bf_u(hi.y);
    r[6] = (short)f2bf_u(hi.z); r[7] = (short)f2bf_u(hi.w);
    return r;
}

__launch_bounds__(256)
__global__ void gemm_kernel(const float* __restrict__ h, const float* cbuf,
                            const float* __restrict__ snorm, const float* __restrict__ W,
                            float* out, int nNodes) {
    __shared__ float rowsq[4][16][4];
    const int tid  = threadIdx.x;
    const int wid  = tid >> 6;
    const int lane = tid & 63;
    const int lr   = lane & 15;
    const int lk   = lane >> 4;
    const int base = blockIdx.x * 64;
    short8 b[2][8];
#pragma unroll
    for (int t = 0; t < 2; ++t) {
        const int wrow = (wid * 2 + t) * 16 + lr;
#pragma unroll
        for (int ks = 0; ks < 8; ++ks)
            b[t][ks] = cvt8(W + wrow * 256 + ks * 32 + lk * 8);
    }
    f32x4 acc[4][2];
#pragma unroll
    for (int rt = 0; rt < 4; ++rt) {
        acc[rt][0] = (f32x4)(0.f);
        acc[rt][1] = (f32x4)(0.f);
        int arow = base + rt * 16 + lr;
        arow = (arow < nNodes) ? arow : (nNodes - 1);
        const float* hp = h    + arow * DIM + lk * 8;
        const float* cp = cbuf + arow * DIM + lk * 8;
#pragma unroll
        for (int ks = 0; ks < 4; ++ks) {
            const short8 a = cvt8(hp + ks * 32);
            acc[rt][0] = __builtin_amdgcn_mfma_f32_16x16x32_bf16(a, b[0][ks], acc[rt][0], 0, 0, 0);
            acc[rt][1] = __builtin_amdgcn_mfma_f32_16x16x32_bf16(a, b[1][ks], acc[rt][1], 0, 0, 0);
        }
#pragma unroll
        for (int ks = 0; ks < 4; ++ks) {
            const short8 a = cvt8(cp + ks * 32);
            acc[rt][0] = __builtin_amdgcn_mfma_f32_16x16x32_bf16(a, b[0][ks + 4], acc[rt][0], 0, 0, 0);
            acc[rt][1] = __builtin_amdgcn_mfma_f32_16x16x32_bf16(a, b[1][ks + 4], acc[rt][1], 0, 0, 0);
        }
#pragma unroll
        for (int r = 0; r < 4; ++r) {
            float sq = acc[rt][0][r] * acc[rt][0][r] + acc[rt][1][r] * acc[rt][1][r];
            sq += __shfl_xor(sq, 1);
            sq += __shfl_xor(sq, 2);
            sq += __shfl_xor(sq, 4);
            sq += __shfl_xor(sq, 8);
            if (lr == 0) rowsq[rt][lk * 4 + r][wid] = sq;
        }
    }
    __syncthreads();
#pragma unroll
    for (int rt = 0; rt < 4; ++rt) {
#pragma unroll
        for (int r = 0; r < 4; ++r) {
            const int row16 = lk * 4 + r;
            const int node  = base + rt * 16 + row16;
            if (node < nNodes) {
                const float nsq = rowsq[rt][row16][0] + rowsq[rt][row16][1]
                                + rowsq[rt][row16][2] + rowsq[rt][row16][3];
                const float scale = 1.0f / fmaxf(sqrtf(nsq), 1e-12f);
                const float sn    = snorm[node];
#pragma unroll
                for (int t = 0; t < 2; ++t) {
                    const int col = (wid * 2 + t) * 16 + lr;
                    out[node * DIM + col] = fmaxf(acc[rt][t][r] * scale, 0.f) * sn;
                }
            }
        }
    }
}

// ---------------- launcher ----------------

extern "C" void kernel_launch(void* const* d_in, const int* in_sizes, int n_in,
                              void* d_out, int out_size, void* d_ws, size_t ws_size,
                              hipStream_t stream) {
    const float* h     = (const float*)d_in[0];
    const float* snorm = (const float*)d_in[1];
    const float* W     = (const float*)d_in[2];
    const int*   src   = (const int*)d_in[3];
    const int*   dst   = (const int*)d_in[4];
    float*       out   = (float*)d_out;

    char* ws = (char*)d_ws;
    int* deg     = (int*)(ws + 0);              // 50000 ints
    int* cursor  = (int*)(ws + 200000);         // 50001 ints -> ends 400004
    int* offsets = (int*)(ws + 400064);         // 50001 ints -> ends 600068
    int* bsum    = (int*)(ws + 600416);         // 196 ints
    int* esrc    = (int*)(ws + 601216);         // 600000 ints -> ends 3001216
    unsigned short* hb = (unsigned short*)(ws + 3001344);    // 12.8 MB
    unsigned short* cb = (unsigned short*)(ws + 15801344);   // 12.8 MB
    unsigned short* Wb = (unsigned short*)(ws + 28601344);   // 64 KB
    const size_t NEED = 28666880;
    const int doCvt = (ws_size >= NEED) ? 1 : 0;

    const int nblocks = (N_NODES_C + 255) / 256;   // 196

    prep_kernel<<<81, 256, 0, stream>>>((int4*)deg, (const float4*)W, (ushort4*)Wb, doCvt);
    count_h_kernel<<<EBLOCKS + HCVT_BLOCKS, 256, 0, stream>>>(dst, deg, (const float4*)h,
                                                              (ushort4*)hb, doCvt);
    scan1_kernel<<<nblocks, 256, 0, stream>>>(deg, offsets, bsum, N_NODES_C);
    scan2_kernel<<<1, 256, 0, stream>>>(bsum, nblocks);
    scan3_kernel<<<nblocks, 256, 0, stream>>>(offsets, bsum, cursor, N_NODES_C);
    fill_kernel<<<EBLOCKS, 256, 0, stream>>>(src, dst, cursor, esrc, N_EDGES_C);

    if (doCvt) {
        agg_bf_kernel<<<(N_NODES_C + 3) / 4, 256, 0, stream>>>(hb, offsets, esrc, cb, N_NODES_C);
        gemm_bf_kernel<<<(N_NODES_C + 31) / 32, 256, 0, stream>>>(hb, cb, snorm, Wb, out, N_NODES_C);
    } else {
        agg_kernel<<<(N_NODES_C + 3) / 4, 256, 0, stream>>>(h, offsets, esrc, out, N_NODES_C);
        gemm_kernel<<<(N_NODES_C + 63) / 64, 256, 0, stream>>>(h, out, snorm, W, out, N_NODES_C);
    }
}